// Round 1
// baseline (651.202 us; speedup 1.0000x reference)
//
#include <hip/hip_runtime.h>

typedef __bf16 bf16x8 __attribute__((ext_vector_type(8)));
typedef float f32x4 __attribute__((ext_vector_type(4)));
typedef unsigned short u16;
typedef u16 u16x8 __attribute__((ext_vector_type(8)));

// Problem constants
#define NB 16     // batch
#define CD 512    // channels
#define NN 4096   // hw
#define O3 1536   // 3*hidden

__device__ __forceinline__ u16 f2bf(float f) {
    union { float f; unsigned int u; } v; v.f = f;
    unsigned int r = v.u + 0x7fffu + ((v.u >> 16) & 1u);
    return (u16)(r >> 16);
}
__device__ __forceinline__ float bf2f(u16 s) {
    union { unsigned int u; float f; } v; v.u = ((unsigned int)s) << 16;
    return v.f;
}

__device__ __forceinline__ void gl2lds16(const u16* g, u16* l) {
    __builtin_amdgcn_global_load_lds(
        (const void __attribute__((address_space(1)))*)g,
        (void __attribute__((address_space(3)))*)l,
        16, 0, 0);
}

// ---------------- convert w_qkv fp32 -> bf16 (row-major [1536][512]) ----------
__global__ void k_convert(const float* __restrict__ in, u16* __restrict__ out, int n) {
    int i = blockIdx.x * 256 + threadIdx.x;
    if (i < n) out[i] = f2bf(in[i]);
}

// ---------------- transpose x[b][c][n] fp32 -> xt[b][n][c] bf16 ---------------
__global__ __launch_bounds__(256) void k_transpose_x(const float* __restrict__ x,
                                                     u16* __restrict__ xt) {
    __shared__ float tile[32][33];
    int b = blockIdx.y;
    int ntile = blockIdx.x & 127;   // 4096/32
    int ctile = blockIdx.x >> 7;    // 512/32
    int tx = threadIdx.x & 31, ty = threadIdx.x >> 5; // 32x8
    const float* xb = x + (size_t)b * CD * NN;
#pragma unroll
    for (int j = 0; j < 4; ++j) {
        int c = ctile * 32 + ty + j * 8;
        tile[ty + j * 8][tx] = xb[(size_t)c * NN + ntile * 32 + tx];
    }
    __syncthreads();
    u16* xtb = xt + (size_t)b * NN * CD;
#pragma unroll
    for (int j = 0; j < 4; ++j) {
        int n = ntile * 32 + ty + j * 8;
        xtb[(size_t)n * CD + ctile * 32 + tx] = f2bf(tile[tx][ty + j * 8]);
    }
}

// ---------------- GEMM1: qkv = Wqkv(1536x512) @ X_b(512x4096) -----------------
// A row-major [o][k], Bt row-major [n][k]; 128x128 tile, BK=32, 4 waves.
// Epilogue: rows [0,512) -> Qt[b][n][c] (transposed, bf16)
//           rows [512,1024) -> K[b][row][n], rows [1024,1536) -> V[b][row][n]
__global__ __launch_bounds__(256, 2) void k_gemm1(
        const u16* __restrict__ A, const u16* __restrict__ Bt,
        u16* __restrict__ qt, u16* __restrict__ kbuf, u16* __restrict__ vbuf) {
    __shared__ __align__(16) u16 As[128 * 32];
    __shared__ __align__(16) u16 Bs[128 * 32];
    const int t = threadIdx.x;
    const int b = blockIdx.y;
    const int ot = blockIdx.x % 12;
    const int nt = blockIdx.x / 12;
    const int lane = t & 63, w = t >> 6;
    const int l15 = lane & 15, quad = lane >> 4;
    const int wm = (w >> 1) * 64, wn = (w & 1) * 64;
    const int r4 = t >> 2;           // staging row 0..63
    const int kc = (t & 3) * 8;      // staging k offset

    const u16* Ab = A + (size_t)(ot * 128) * CD;
    const u16* Bb = Bt + (size_t)b * NN * CD + (size_t)(nt * 128) * CD;

    f32x4 acc[4][4] = {};

    for (int k0 = 0; k0 < CD; k0 += 32) {
        __syncthreads();
        gl2lds16(Ab + (size_t)r4 * CD + k0 + kc,        &As[t * 8]);
        gl2lds16(Ab + (size_t)(r4 + 64) * CD + k0 + kc, &As[2048 + t * 8]);
        gl2lds16(Bb + (size_t)r4 * CD + k0 + kc,        &Bs[t * 8]);
        gl2lds16(Bb + (size_t)(r4 + 64) * CD + k0 + kc, &Bs[2048 + t * 8]);
        __syncthreads();
        bf16x8 af[4], bfr[4];
#pragma unroll
        for (int mi = 0; mi < 4; ++mi)
            af[mi] = *(const bf16x8*)&As[(wm + mi * 16 + l15) * 32 + quad * 8];
#pragma unroll
        for (int ni = 0; ni < 4; ++ni)
            bfr[ni] = *(const bf16x8*)&Bs[(wn + ni * 16 + l15) * 32 + quad * 8];
#pragma unroll
        for (int mi = 0; mi < 4; ++mi)
#pragma unroll
            for (int ni = 0; ni < 4; ++ni)
                acc[mi][ni] = __builtin_amdgcn_mfma_f32_16x16x32_bf16(
                    af[mi], bfr[ni], acc[mi][ni], 0, 0, 0);
    }

    const int sec = ot >> 2;                 // 0=Q 1=K 2=V
    const int lrowbase = ot * 128 - sec * 512;
#pragma unroll
    for (int mi = 0; mi < 4; ++mi) {
        int lr = lrowbase + wm + mi * 16 + quad * 4;
#pragma unroll
        for (int ni = 0; ni < 4; ++ni) {
            int nc = nt * 128 + wn + ni * 16 + l15;
            if (sec == 0) {
                ushort4 pk;
                pk.x = f2bf(acc[mi][ni][0]); pk.y = f2bf(acc[mi][ni][1]);
                pk.z = f2bf(acc[mi][ni][2]); pk.w = f2bf(acc[mi][ni][3]);
                *(ushort4*)&qt[((size_t)b * NN + nc) * CD + lr] = pk;
            } else {
                u16* dst = (sec == 1) ? kbuf : vbuf;
#pragma unroll
                for (int r = 0; r < 4; ++r)
                    dst[((size_t)(b * 512 + lr + r)) * NN + nc] = f2bf(acc[mi][ni][r]);
            }
        }
    }
}

// ---------------- softmax over n=4096, in place on kbuf (8192 rows) -----------
__global__ __launch_bounds__(256) void k_softmax(u16* __restrict__ kbuf) {
    const int row = blockIdx.x;
    u16* p = kbuf + (size_t)row * NN;
    const int t = threadIdx.x;
    const int lane = t & 63, w = t >> 6;

    float v[16];
    u16x8 u0 = *(const u16x8*)&p[t * 16];
    u16x8 u1 = *(const u16x8*)&p[t * 16 + 8];
#pragma unroll
    for (int i = 0; i < 8; ++i) { v[i] = bf2f(u0[i]); v[8 + i] = bf2f(u1[i]); }

    float mx = -3.0e38f;
#pragma unroll
    for (int i = 0; i < 16; ++i) mx = fmaxf(mx, v[i]);
#pragma unroll
    for (int off = 32; off; off >>= 1) mx = fmaxf(mx, __shfl_xor(mx, off));
    __shared__ float redm[4];
    if (lane == 0) redm[w] = mx;
    __syncthreads();
    mx = fmaxf(fmaxf(redm[0], redm[1]), fmaxf(redm[2], redm[3]));

    float s = 0.f;
#pragma unroll
    for (int i = 0; i < 16; ++i) { v[i] = __expf(v[i] - mx); s += v[i]; }
#pragma unroll
    for (int off = 32; off; off >>= 1) s += __shfl_xor(s, off);
    __shared__ float reds[4];
    if (lane == 0) reds[w] = s;
    __syncthreads();
    s = reds[0] + reds[1] + reds[2] + reds[3];
    float inv = 1.f / s;

    u16x8 o0, o1;
#pragma unroll
    for (int i = 0; i < 8; ++i) { o0[i] = f2bf(v[i] * inv); o1[i] = f2bf(v[8 + i] * inv); }
    *(u16x8*)&p[t * 16] = o0;
    *(u16x8*)&p[t * 16 + 8] = o1;
}

// ---------------- context[bh][c][d] += Ksm(64x4096) @ V^T, n-chunked ----------
__global__ __launch_bounds__(256) void k_context(const u16* __restrict__ ksm,
                                                 const u16* __restrict__ vbuf,
                                                 float* __restrict__ ctx) {
    const int bh = blockIdx.y;        // 0..127
    const int chunk = blockIdx.x;     // 0..7, each 512 of n
    const int t = threadIdx.x, lane = t & 63, w = t >> 6;
    const int l15 = lane & 15, quad = lane >> 4;

    const u16* arow = ksm + (size_t)(bh * 64 + w * 16 + l15) * NN;
    const u16* vb = vbuf + (size_t)bh * 64 * NN;

    f32x4 acc[4] = {};
    for (int i = 0; i < 16; ++i) {
        int n0 = chunk * 512 + i * 32 + quad * 8;
        bf16x8 a = *(const bf16x8*)&arow[n0];
#pragma unroll
        for (int di = 0; di < 4; ++di) {
            bf16x8 bb = *(const bf16x8*)&vb[(size_t)(di * 16 + l15) * NN + n0];
            acc[di] = __builtin_amdgcn_mfma_f32_16x16x32_bf16(a, bb, acc[di], 0, 0, 0);
        }
    }
    const int c = w * 16 + quad * 4;
#pragma unroll
    for (int di = 0; di < 4; ++di) {
        int d = di * 16 + l15;
#pragma unroll
        for (int r = 0; r < 4; ++r)
            atomicAdd(&ctx[((size_t)bh * 64 + c + r) * 64 + d], acc[di][r]);
    }
}

// ---------------- W_eff[b][o][h*64+c] = sum_d wout[o][h*64+d]*ctx[b][h][c][d] --
__global__ __launch_bounds__(256) void k_weff(const float* __restrict__ wout,
                                              const float* __restrict__ ctx,
                                              u16* __restrict__ weff) {
    int idx = blockIdx.x * 256 + threadIdx.x;   // 16*512*512
    int b = idx >> 18;
    int o = (idx >> 9) & 511;
    int hc = idx & 511;
    int h = hc >> 6, c = hc & 63;
    const float* wr = wout + o * 512 + h * 64;
    const float* cr = ctx + (((size_t)b * 8 + h) * 64 + c) * 64;
    float s = 0.f;
#pragma unroll
    for (int d = 0; d < 64; ++d) s += wr[d] * cr[d];
    weff[idx] = f2bf(s);
}

// ---------------- GEMM2: Y_b = W_eff_b(512x512) @ Q_b + b_out -----------------
__global__ __launch_bounds__(256, 2) void k_gemm2(
        const u16* __restrict__ weff, const u16* __restrict__ qt,
        const float* __restrict__ bout, float* __restrict__ y) {
    __shared__ __align__(16) u16 As[128 * 32];
    __shared__ __align__(16) u16 Bs[128 * 32];
    const int t = threadIdx.x;
    const int b = blockIdx.y;
    const int ot = blockIdx.x & 3;
    const int nt = blockIdx.x >> 2;
    const int lane = t & 63, w = t >> 6;
    const int l15 = lane & 15, quad = lane >> 4;
    const int wm = (w >> 1) * 64, wn = (w & 1) * 64;
    const int r4 = t >> 2;
    const int kc = (t & 3) * 8;

    const u16* Ab = weff + (size_t)b * 512 * 512 + (size_t)(ot * 128) * CD;
    const u16* Bb = qt + (size_t)b * NN * CD + (size_t)(nt * 128) * CD;

    f32x4 acc[4][4] = {};

    for (int k0 = 0; k0 < CD; k0 += 32) {
        __syncthreads();
        gl2lds16(Ab + (size_t)r4 * CD + k0 + kc,        &As[t * 8]);
        gl2lds16(Ab + (size_t)(r4 + 64) * CD + k0 + kc, &As[2048 + t * 8]);
        gl2lds16(Bb + (size_t)r4 * CD + k0 + kc,        &Bs[t * 8]);
        gl2lds16(Bb + (size_t)(r4 + 64) * CD + k0 + kc, &Bs[2048 + t * 8]);
        __syncthreads();
        bf16x8 af[4], bfr[4];
#pragma unroll
        for (int mi = 0; mi < 4; ++mi)
            af[mi] = *(const bf16x8*)&As[(wm + mi * 16 + l15) * 32 + quad * 8];
#pragma unroll
        for (int ni = 0; ni < 4; ++ni)
            bfr[ni] = *(const bf16x8*)&Bs[(wn + ni * 16 + l15) * 32 + quad * 8];
#pragma unroll
        for (int mi = 0; mi < 4; ++mi)
#pragma unroll
            for (int ni = 0; ni < 4; ++ni)
                acc[mi][ni] = __builtin_amdgcn_mfma_f32_16x16x32_bf16(
                    af[mi], bfr[ni], acc[mi][ni], 0, 0, 0);
    }

#pragma unroll
    for (int mi = 0; mi < 4; ++mi) {
        int o = ot * 128 + wm + mi * 16 + quad * 4;
#pragma unroll
        for (int ni = 0; ni < 4; ++ni) {
            int nc = nt * 128 + wn + ni * 16 + l15;
#pragma unroll
            for (int r = 0; r < 4; ++r)
                y[((size_t)(b * 512 + o + r)) * NN + nc] = acc[mi][ni][r] + bout[o + r];
        }
    }
}

extern "C" void kernel_launch(void* const* d_in, const int* in_sizes, int n_in,
                              void* d_out, int out_size, void* d_ws, size_t ws_size,
                              hipStream_t stream) {
    const float* x    = (const float*)d_in[0];
    const float* wqkv = (const float*)d_in[1];
    const float* wout = (const float*)d_in[2];
    const float* bout = (const float*)d_in[3];
    float* y = (float*)d_out;

    char* ws = (char*)d_ws;
    // workspace layout (bytes)
    u16*   xt   = (u16*)(ws);                       //  67,108,864  xt[b][n][c] bf16
    u16*   wqb  = (u16*)(ws + 67108864);            //   1,572,864  wqkv bf16
    u16*   qt   = (u16*)(ws + 68681728);            //  67,108,864  Qt[b][n][c] bf16
    u16*   kbuf = (u16*)(ws + 135790592);           //  67,108,864  K / Ksm [b*512][n]
    u16*   vbuf = (u16*)(ws + 202899456);           //  67,108,864  V [b*512][n]
    float* ctx  = (float*)(ws + 270008320);         //   8,388,608  context fp32
    u16*   weff = (u16*)(ws + 278396928);           //   8,388,608  W_eff bf16
    // total ~287 MB

    hipMemsetAsync(ctx, 0, (size_t)NB * 8 * 64 * 64 * sizeof(float), stream);

    k_convert<<<(O3 * CD + 255) / 256, 256, 0, stream>>>(wqkv, wqb, O3 * CD);
    k_transpose_x<<<dim3(128 * 16, NB), 256, 0, stream>>>(x, xt);
    k_gemm1<<<dim3(12 * 32, NB), 256, 0, stream>>>(wqb, xt, qt, kbuf, vbuf);
    k_softmax<<<NB * 512, 256, 0, stream>>>(kbuf);
    k_context<<<dim3(8, NB * 8), 256, 0, stream>>>(kbuf, vbuf, ctx);
    k_weff<<<(NB * 512 * 512) / 256, 256, 0, stream>>>(wout, ctx, weff);
    k_gemm2<<<dim3(4 * 32, NB), 256, 0, stream>>>(weff, qt, bout, y);
}

// Round 2
// 599.842 us; speedup vs baseline: 1.0856x; 1.0856x over previous
//
#include <hip/hip_runtime.h>
#include <string.h>

typedef __bf16 bf16x8 __attribute__((ext_vector_type(8)));
typedef float f32x4 __attribute__((ext_vector_type(4)));
typedef unsigned short u16;
typedef u16 u16x8 __attribute__((ext_vector_type(8)));

#define NB 16     // batch
#define CD 512    // channels
#define NN 4096   // hw
#define O3 1536   // 3*hidden

__device__ __forceinline__ u16 f2bf(float f) {
    union { float f; unsigned int u; } v; v.f = f;
    unsigned int r = v.u + 0x7fffu + ((v.u >> 16) & 1u);
    return (u16)(r >> 16);
}
__device__ __forceinline__ float bf2f(u16 s) {
    union { unsigned int u; float f; } v; v.u = ((unsigned int)s) << 16;
    return v.f;
}

__device__ __forceinline__ void gl2lds16(const u16* g, u16* l) {
    __builtin_amdgcn_global_load_lds(
        (const void __attribute__((address_space(1)))*)g,
        (void __attribute__((address_space(3)))*)l,
        16, 0, 0);
}

// ---------------- convert w_qkv fp32 -> bf16 (row-major [1536][512]) ----------
__global__ void k_convert(const float* __restrict__ in, u16* __restrict__ out, int n) {
    int i = blockIdx.x * 256 + threadIdx.x;
    if (i < n) out[i] = f2bf(in[i]);
}

// ---------------- transpose x[b][c][n] fp32 -> xt[b][n][c] bf16, 64x64 tiles --
__global__ __launch_bounds__(256) void k_transpose_x(const float* __restrict__ x,
                                                     u16* __restrict__ xt) {
    __shared__ float tile[64][65];
    const int b = blockIdx.y;
    const int ntile = blockIdx.x & 63;   // 4096/64
    const int ctile = blockIdx.x >> 6;   // 512/64
    const int t = threadIdx.x;
    const int r = t >> 2;                // 0..63 (row)
    const int q = t & 3;                 // 4 threads per row

    const float* xb = x + ((size_t)b * CD + ctile * 64 + r) * NN + ntile * 64;
#pragma unroll
    for (int j = 0; j < 4; ++j) {
        float4 v = *(const float4*)&xb[q * 16 + j * 4];
        tile[r][q * 16 + j * 4 + 0] = v.x;
        tile[r][q * 16 + j * 4 + 1] = v.y;
        tile[r][q * 16 + j * 4 + 2] = v.z;
        tile[r][q * 16 + j * 4 + 3] = v.w;
    }
    __syncthreads();
    // write: row = n (r), 16 c values per thread -> 128B per 4 threads
    u16* xtb = xt + ((size_t)b * NN + ntile * 64 + r) * CD + ctile * 64 + q * 16;
    u16x8 o0, o1;
#pragma unroll
    for (int j = 0; j < 8; ++j) {
        o0[j] = f2bf(tile[q * 16 + j][r]);
        o1[j] = f2bf(tile[q * 16 + 8 + j][r]);
    }
    *(u16x8*)&xtb[0] = o0;
    *(u16x8*)&xtb[8] = o1;
}

// ---------------- GEMM1: qkv = Wqkv(1536x512) @ X_b(512x4096) -----------------
// 128x128 tile, BK=64, 4 waves, XCD swizzle. Epilogue:
//   rows [0,512) -> Qt[b][n][c] bf16 ; [512,1024) -> K[b][r][n] ; [1024,1536) -> V
__global__ __launch_bounds__(256, 2) void k_gemm1(
        const u16* __restrict__ A, const u16* __restrict__ Bt,
        u16* __restrict__ qt, u16* __restrict__ kbuf, u16* __restrict__ vbuf) {
    __shared__ __align__(16) u16 As[128 * 64];
    __shared__ __align__(16) u16 Bs[128 * 64];
    const int t = threadIdx.x;
    const int gid = blockIdx.x;
    // XCD swizzle: 12 o-tiles of same (b,nt) land on one XCD consecutively
    const int xcd = gid & 7;
    const int j = gid >> 3;
    const int ot = j % 12;
    const int bn = (j / 12) * 8 + xcd;   // 0..511
    const int b = bn >> 5;
    const int nt = bn & 31;

    const int lane = t & 63, w = t >> 6;
    const int l15 = lane & 15, quad = lane >> 4;
    const int wm = (w >> 1) * 64, wn = (w & 1) * 64;
    const int srow = t >> 3;             // staging row 0..31
    const int kc = (t & 7) * 8;          // staging k offset

    const u16* Ab = A + (size_t)(ot * 128) * CD;
    const u16* Bb = Bt + (size_t)b * NN * CD + (size_t)(nt * 128) * CD;

    f32x4 acc[4][4] = {};

    for (int k0 = 0; k0 < CD; k0 += 64) {
        __syncthreads();
        gl2lds16(Ab + (size_t)(srow     ) * CD + k0 + kc, &As[t * 8]);
        gl2lds16(Ab + (size_t)(srow + 32) * CD + k0 + kc, &As[2048 + t * 8]);
        gl2lds16(Ab + (size_t)(srow + 64) * CD + k0 + kc, &As[4096 + t * 8]);
        gl2lds16(Ab + (size_t)(srow + 96) * CD + k0 + kc, &As[6144 + t * 8]);
        gl2lds16(Bb + (size_t)(srow     ) * CD + k0 + kc, &Bs[t * 8]);
        gl2lds16(Bb + (size_t)(srow + 32) * CD + k0 + kc, &Bs[2048 + t * 8]);
        gl2lds16(Bb + (size_t)(srow + 64) * CD + k0 + kc, &Bs[4096 + t * 8]);
        gl2lds16(Bb + (size_t)(srow + 96) * CD + k0 + kc, &Bs[6144 + t * 8]);
        __syncthreads();
#pragma unroll
        for (int h = 0; h < 2; ++h) {
            bf16x8 af[4], bfr[4];
#pragma unroll
            for (int mi = 0; mi < 4; ++mi)
                af[mi] = *(const bf16x8*)&As[(wm + mi * 16 + l15) * 64 + h * 32 + quad * 8];
#pragma unroll
            for (int ni = 0; ni < 4; ++ni)
                bfr[ni] = *(const bf16x8*)&Bs[(wn + ni * 16 + l15) * 64 + h * 32 + quad * 8];
#pragma unroll
            for (int mi = 0; mi < 4; ++mi)
#pragma unroll
                for (int ni = 0; ni < 4; ++ni)
                    acc[mi][ni] = __builtin_amdgcn_mfma_f32_16x16x32_bf16(
                        af[mi], bfr[ni], acc[mi][ni], 0, 0, 0);
        }
    }

    const int sec = ot >> 2;                 // 0=Q 1=K 2=V
    const int lrowbase = ot * 128 - sec * 512;
#pragma unroll
    for (int mi = 0; mi < 4; ++mi) {
        int lr = lrowbase + wm + mi * 16 + quad * 4;
#pragma unroll
        for (int ni = 0; ni < 4; ++ni) {
            int nc = nt * 128 + wn + ni * 16 + l15;
            if (sec == 0) {
                ushort4 pk;
                pk.x = f2bf(acc[mi][ni][0]); pk.y = f2bf(acc[mi][ni][1]);
                pk.z = f2bf(acc[mi][ni][2]); pk.w = f2bf(acc[mi][ni][3]);
                *(ushort4*)&qt[((size_t)b * NN + nc) * CD + lr] = pk;
            } else {
                u16* dst = (sec == 1) ? kbuf : vbuf;
#pragma unroll
                for (int r = 0; r < 4; ++r)
                    dst[((size_t)(b * 512 + lr + r)) * NN + nc] = f2bf(acc[mi][ni][r]);
            }
        }
    }
}

// -------- fused exp + context: ctx[bh][c][d] += sum_n exp(K[c][n]) V[d][n] ----
// lsum[bh][c] += sum_n exp(K[c][n]); normalization folded into k_weff.
__global__ __launch_bounds__(256) void k_ctx(const u16* __restrict__ kbuf,
                                             const u16* __restrict__ vbuf,
                                             float* __restrict__ ctx,
                                             float* __restrict__ lsum) {
    const int bh = blockIdx.y;           // 0..127
    const int chunk = blockIdx.x;        // 0..3, 1024 n each
    const int t = threadIdx.x, lane = t & 63, w = t >> 6;
    const int l15 = lane & 15, quad = lane >> 4;
    const int cb = w * 16;               // wave's 16 c-rows

    const u16* krow = kbuf + (size_t)(bh * 64 + cb + l15) * NN;
    const u16* vb   = vbuf + (size_t)bh * 64 * NN;

    f32x4 acc[4] = {};
    float ls = 0.f;
    for (int i = 0; i < 32; ++i) {
        int n0 = chunk * 1024 + i * 32 + quad * 8;
        u16x8 ku = *(const u16x8*)&krow[n0];
        u16x8 afu;
#pragma unroll
        for (int jj = 0; jj < 8; ++jj) {
            float ev = __expf(fminf(bf2f(ku[jj]), 30.f));
            ls += ev;
            afu[jj] = f2bf(ev);
        }
        bf16x8 af = __builtin_bit_cast(bf16x8, afu);
#pragma unroll
        for (int di = 0; di < 4; ++di) {
            bf16x8 bfv = *(const bf16x8*)&vb[(size_t)(di * 16 + l15) * NN + n0];
            acc[di] = __builtin_amdgcn_mfma_f32_16x16x32_bf16(af, bfv, acc[di], 0, 0, 0);
        }
    }
    // per-row sum: lanes {l15, l15+16, l15+32, l15+48} hold partials
    ls += __shfl_xor(ls, 16);
    ls += __shfl_xor(ls, 32);
    if (quad == 0) atomicAdd(&lsum[(size_t)bh * 64 + cb + l15], ls);

    const int c = cb + quad * 4;
#pragma unroll
    for (int di = 0; di < 4; ++di) {
        int d = di * 16 + l15;
#pragma unroll
        for (int r = 0; r < 4; ++r)
            atomicAdd(&ctx[((size_t)bh * 64 + c + r) * 64 + d], acc[di][r]);
    }
}

// ---- W_eff[b][o][h*64+c] = (1/l_c) * sum_d wout[o][h*64+d]*ctx[b][h][c][d] ---
__global__ __launch_bounds__(256) void k_weff(const float* __restrict__ wout,
                                              const float* __restrict__ ctx,
                                              const float* __restrict__ lsum,
                                              u16* __restrict__ weff) {
    int idx = blockIdx.x * 256 + threadIdx.x;   // 16*512*512
    int b = idx >> 18;
    int o = (idx >> 9) & 511;
    int hc = idx & 511;
    int h = hc >> 6, c = hc & 63;
    const float* wr = wout + o * 512 + h * 64;
    const float* cr = ctx + (((size_t)b * 8 + h) * 64 + c) * 64;
    float s = 0.f;
#pragma unroll
    for (int d = 0; d < 64; ++d) s += wr[d] * cr[d];
    s *= 1.0f / lsum[((size_t)b * 8 + h) * 64 + c];
    weff[idx] = f2bf(s);
}

// ---------------- GEMM2: Y_b = W_eff_b(512x512) @ Q_b + b_out -----------------
__global__ __launch_bounds__(256, 2) void k_gemm2(
        const u16* __restrict__ weff, const u16* __restrict__ qt,
        const float* __restrict__ bout, float* __restrict__ y) {
    __shared__ __align__(16) u16 As[128 * 64];
    __shared__ __align__(16) u16 Bs[128 * 64];
    const int t = threadIdx.x;
    const int gid = blockIdx.x;
    const int xcd = gid & 7;
    const int j = gid >> 3;
    const int ot = j & 3;
    const int bn = (j >> 2) * 8 + xcd;   // 0..511
    const int b = bn >> 5;
    const int nt = bn & 31;

    const int lane = t & 63, w = t >> 6;
    const int l15 = lane & 15, quad = lane >> 4;
    const int wm = (w >> 1) * 64, wn = (w & 1) * 64;
    const int srow = t >> 3;
    const int kc = (t & 7) * 8;

    const u16* Ab = weff + (size_t)b * 512 * 512 + (size_t)(ot * 128) * CD;
    const u16* Bb = qt + (size_t)b * NN * CD + (size_t)(nt * 128) * CD;

    f32x4 acc[4][4] = {};

    for (int k0 = 0; k0 < CD; k0 += 64) {
        __syncthreads();
        gl2lds16(Ab + (size_t)(srow     ) * CD + k0 + kc, &As[t * 8]);
        gl2lds16(Ab + (size_t)(srow + 32) * CD + k0 + kc, &As[2048 + t * 8]);
        gl2lds16(Ab + (size_t)(srow + 64) * CD + k0 + kc, &As[4096 + t * 8]);
        gl2lds16(Ab + (size_t)(srow + 96) * CD + k0 + kc, &As[6144 + t * 8]);
        gl2lds16(Bb + (size_t)(srow     ) * CD + k0 + kc, &Bs[t * 8]);
        gl2lds16(Bb + (size_t)(srow + 32) * CD + k0 + kc, &Bs[2048 + t * 8]);
        gl2lds16(Bb + (size_t)(srow + 64) * CD + k0 + kc, &Bs[4096 + t * 8]);
        gl2lds16(Bb + (size_t)(srow + 96) * CD + k0 + kc, &Bs[6144 + t * 8]);
        __syncthreads();
#pragma unroll
        for (int h = 0; h < 2; ++h) {
            bf16x8 af[4], bfr[4];
#pragma unroll
            for (int mi = 0; mi < 4; ++mi)
                af[mi] = *(const bf16x8*)&As[(wm + mi * 16 + l15) * 64 + h * 32 + quad * 8];
#pragma unroll
            for (int ni = 0; ni < 4; ++ni)
                bfr[ni] = *(const bf16x8*)&Bs[(wn + ni * 16 + l15) * 64 + h * 32 + quad * 8];
#pragma unroll
            for (int mi = 0; mi < 4; ++mi)
#pragma unroll
                for (int ni = 0; ni < 4; ++ni)
                    acc[mi][ni] = __builtin_amdgcn_mfma_f32_16x16x32_bf16(
                        af[mi], bfr[ni], acc[mi][ni], 0, 0, 0);
        }
    }

#pragma unroll
    for (int mi = 0; mi < 4; ++mi) {
        int o = ot * 128 + wm + mi * 16 + quad * 4;
#pragma unroll
        for (int ni = 0; ni < 4; ++ni) {
            int nc = nt * 128 + wn + ni * 16 + l15;
#pragma unroll
            for (int r = 0; r < 4; ++r)
                y[((size_t)(b * 512 + o + r)) * NN + nc] = acc[mi][ni][r] + bout[o + r];
        }
    }
}

extern "C" void kernel_launch(void* const* d_in, const int* in_sizes, int n_in,
                              void* d_out, int out_size, void* d_ws, size_t ws_size,
                              hipStream_t stream) {
    const float* x    = (const float*)d_in[0];
    const float* wqkv = (const float*)d_in[1];
    const float* wout = (const float*)d_in[2];
    const float* bout = (const float*)d_in[3];
    float* y = (float*)d_out;

    char* ws = (char*)d_ws;
    u16*   xt   = (u16*)(ws);                       //  67,108,864  xt[b][n][c] bf16
    u16*   wqb  = (u16*)(ws + 67108864);            //   1,572,864  wqkv bf16
    u16*   qt   = (u16*)(ws + 68681728);            //  67,108,864  Qt[b][n][c] bf16
    u16*   kbuf = (u16*)(ws + 135790592);           //  67,108,864  K raw [b*512][n]
    u16*   vbuf = (u16*)(ws + 202899456);           //  67,108,864  V [b*512][n]
    float* ctx  = (float*)(ws + 270008320);         //   2,097,152  context fp32 (unnorm)
    float* lsum = (float*)(ws + 272105472);         //      32,768  row sums
    u16*   weff = (u16*)(ws + 272138240);           //   8,388,608  W_eff bf16

    hipMemsetAsync(ctx, 0, 2097152 + 32768, stream);  // ctx + lsum contiguous

    k_convert<<<(O3 * CD + 255) / 256, 256, 0, stream>>>(wqkv, wqb, O3 * CD);
    k_transpose_x<<<dim3(64 * 8, NB), 256, 0, stream>>>(x, xt);
    k_gemm1<<<12 * 32 * NB, 256, 0, stream>>>(wqb, xt, qt, kbuf, vbuf);
    k_ctx<<<dim3(4, NB * 8), 256, 0, stream>>>(kbuf, vbuf, ctx, lsum);
    k_weff<<<(NB * 512 * 512) / 256, 256, 0, stream>>>(wout, ctx, lsum, weff);
    k_gemm2<<<4 * 32 * NB, 256, 0, stream>>>(weff, qt, bout, y);
}

// Round 3
// 551.310 us; speedup vs baseline: 1.1812x; 1.0880x over previous
//
#include <hip/hip_runtime.h>
#include <string.h>

typedef __bf16 bf16x8 __attribute__((ext_vector_type(8)));
typedef float f32x4 __attribute__((ext_vector_type(4)));
typedef unsigned short u16;
typedef u16 u16x8 __attribute__((ext_vector_type(8)));

#define NB 16     // batch
#define CD 512    // channels
#define NN 4096   // hw
#define O3 1536   // 3*hidden

__device__ __forceinline__ u16 f2bf(float f) {
    union { float f; unsigned int u; } v; v.f = f;
    unsigned int r = v.u + 0x7fffu + ((v.u >> 16) & 1u);
    return (u16)(r >> 16);
}
__device__ __forceinline__ float bf2f(u16 s) {
    union { unsigned int u; float f; } v; v.u = ((unsigned int)s) << 16;
    return v.f;
}

__device__ __forceinline__ void gl2lds16(const u16* g, u16* l) {
    __builtin_amdgcn_global_load_lds(
        (const void __attribute__((address_space(1)))*)g,
        (void __attribute__((address_space(3)))*)l,
        16, 0, 0);
}

// ---------------- convert w_qkv fp32 -> bf16 (row-major [1536][512]) ----------
__global__ void k_convert(const float* __restrict__ in, u16* __restrict__ out, int n) {
    int i = blockIdx.x * 256 + threadIdx.x;
    if (i < n) out[i] = f2bf(in[i]);
}

// ---------------- transpose x[b][c][n] fp32 -> xt[b][n][c] bf16, 64x64 tiles --
__global__ __launch_bounds__(256) void k_transpose_x(const float* __restrict__ x,
                                                     u16* __restrict__ xt) {
    __shared__ float tile[64][65];
    const int b = blockIdx.y;
    const int ntile = blockIdx.x & 63;   // 4096/64
    const int ctile = blockIdx.x >> 6;   // 512/64
    const int t = threadIdx.x;
    const int r = t >> 2;                // 0..63 (row)
    const int q = t & 3;                 // 4 threads per row

    const float* xb = x + ((size_t)b * CD + ctile * 64 + r) * NN + ntile * 64;
#pragma unroll
    for (int j = 0; j < 4; ++j) {
        float4 v = *(const float4*)&xb[q * 16 + j * 4];
        tile[r][q * 16 + j * 4 + 0] = v.x;
        tile[r][q * 16 + j * 4 + 1] = v.y;
        tile[r][q * 16 + j * 4 + 2] = v.z;
        tile[r][q * 16 + j * 4 + 3] = v.w;
    }
    __syncthreads();
    // write: row = n (r), 16 c values per thread -> 128B per 4 threads
    u16* xtb = xt + ((size_t)b * NN + ntile * 64 + r) * CD + ctile * 64 + q * 16;
    u16x8 o0, o1;
#pragma unroll
    for (int j = 0; j < 8; ++j) {
        o0[j] = f2bf(tile[q * 16 + j][r]);
        o1[j] = f2bf(tile[q * 16 + 8 + j][r]);
    }
    *(u16x8*)&xtb[0] = o0;
    *(u16x8*)&xtb[8] = o1;
}

// ---------------- GEMM1: qkv = Wqkv(1536x512) @ X_b(512x4096) -----------------
// 128x128 tile, BK=64, 4 waves, XCD swizzle. Epilogue:
//   rows [0,512) -> Qt[b][n][c] bf16 ; [512,1024) -> K[b][r][n] ; [1024,1536) -> V
__global__ __launch_bounds__(256, 2) void k_gemm1(
        const u16* __restrict__ A, const u16* __restrict__ Bt,
        u16* __restrict__ qt, u16* __restrict__ kbuf, u16* __restrict__ vbuf) {
    __shared__ __align__(16) u16 As[128 * 64];
    __shared__ __align__(16) u16 Bs[128 * 64];
    const int t = threadIdx.x;
    const int gid = blockIdx.x;
    // XCD swizzle: 12 o-tiles of same (b,nt) land on one XCD consecutively
    const int xcd = gid & 7;
    const int j = gid >> 3;
    const int ot = j % 12;
    const int bn = (j / 12) * 8 + xcd;   // 0..511
    const int b = bn >> 5;
    const int nt = bn & 31;

    const int lane = t & 63, w = t >> 6;
    const int l15 = lane & 15, quad = lane >> 4;
    const int wm = (w >> 1) * 64, wn = (w & 1) * 64;
    const int srow = t >> 3;             // staging row 0..31
    const int kc = (t & 7) * 8;          // staging k offset

    const u16* Ab = A + (size_t)(ot * 128) * CD;
    const u16* Bb = Bt + (size_t)b * NN * CD + (size_t)(nt * 128) * CD;

    f32x4 acc[4][4] = {};

    for (int k0 = 0; k0 < CD; k0 += 64) {
        __syncthreads();
        gl2lds16(Ab + (size_t)(srow     ) * CD + k0 + kc, &As[t * 8]);
        gl2lds16(Ab + (size_t)(srow + 32) * CD + k0 + kc, &As[2048 + t * 8]);
        gl2lds16(Ab + (size_t)(srow + 64) * CD + k0 + kc, &As[4096 + t * 8]);
        gl2lds16(Ab + (size_t)(srow + 96) * CD + k0 + kc, &As[6144 + t * 8]);
        gl2lds16(Bb + (size_t)(srow     ) * CD + k0 + kc, &Bs[t * 8]);
        gl2lds16(Bb + (size_t)(srow + 32) * CD + k0 + kc, &Bs[2048 + t * 8]);
        gl2lds16(Bb + (size_t)(srow + 64) * CD + k0 + kc, &Bs[4096 + t * 8]);
        gl2lds16(Bb + (size_t)(srow + 96) * CD + k0 + kc, &Bs[6144 + t * 8]);
        __syncthreads();
#pragma unroll
        for (int h = 0; h < 2; ++h) {
            bf16x8 af[4], bfr[4];
#pragma unroll
            for (int mi = 0; mi < 4; ++mi)
                af[mi] = *(const bf16x8*)&As[(wm + mi * 16 + l15) * 64 + h * 32 + quad * 8];
#pragma unroll
            for (int ni = 0; ni < 4; ++ni)
                bfr[ni] = *(const bf16x8*)&Bs[(wn + ni * 16 + l15) * 64 + h * 32 + quad * 8];
#pragma unroll
            for (int mi = 0; mi < 4; ++mi)
#pragma unroll
                for (int ni = 0; ni < 4; ++ni)
                    acc[mi][ni] = __builtin_amdgcn_mfma_f32_16x16x32_bf16(
                        af[mi], bfr[ni], acc[mi][ni], 0, 0, 0);
        }
    }

    const int sec = ot >> 2;                 // 0=Q 1=K 2=V
    const int lrowbase = ot * 128 - sec * 512;
#pragma unroll
    for (int mi = 0; mi < 4; ++mi) {
        int lr = lrowbase + wm + mi * 16 + quad * 4;
#pragma unroll
        for (int ni = 0; ni < 4; ++ni) {
            int nc = nt * 128 + wn + ni * 16 + l15;
            if (sec == 0) {
                ushort4 pk;
                pk.x = f2bf(acc[mi][ni][0]); pk.y = f2bf(acc[mi][ni][1]);
                pk.z = f2bf(acc[mi][ni][2]); pk.w = f2bf(acc[mi][ni][3]);
                *(ushort4*)&qt[((size_t)b * NN + nc) * CD + lr] = pk;
            } else {
                u16* dst = (sec == 1) ? kbuf : vbuf;
#pragma unroll
                for (int r = 0; r < 4; ++r)
                    dst[((size_t)(b * 512 + lr + r)) * NN + nc] = f2bf(acc[mi][ni][r]);
            }
        }
    }
}

// -------- fused exp + context: ctxT[bh][d][c] += sum_n exp(K[c][n]) V[d][n] ---
// Stored TRANSPOSED (d-major) so k_weff reads coalesce on c.
// lsum[bh][c] += sum_n exp(K[c][n]); normalization folded into k_weff.
__global__ __launch_bounds__(256) void k_ctx(const u16* __restrict__ kbuf,
                                             const u16* __restrict__ vbuf,
                                             float* __restrict__ ctxT,
                                             float* __restrict__ lsum) {
    const int bh = blockIdx.y;           // 0..127
    const int chunk = blockIdx.x;        // 0..3, 1024 n each
    const int t = threadIdx.x, lane = t & 63, w = t >> 6;
    const int l15 = lane & 15, quad = lane >> 4;
    const int cb = w * 16;               // wave's 16 c-rows

    const u16* krow = kbuf + (size_t)(bh * 64 + cb + l15) * NN;
    const u16* vb   = vbuf + (size_t)bh * 64 * NN;

    f32x4 acc[4] = {};
    float ls = 0.f;
    for (int i = 0; i < 32; ++i) {
        int n0 = chunk * 1024 + i * 32 + quad * 8;
        u16x8 ku = *(const u16x8*)&krow[n0];
        u16x8 afu;
#pragma unroll
        for (int jj = 0; jj < 8; ++jj) {
            float ev = __expf(fminf(bf2f(ku[jj]), 30.f));
            ls += ev;
            afu[jj] = f2bf(ev);
        }
        bf16x8 af = __builtin_bit_cast(bf16x8, afu);
#pragma unroll
        for (int di = 0; di < 4; ++di) {
            bf16x8 bfv = *(const bf16x8*)&vb[(size_t)(di * 16 + l15) * NN + n0];
            acc[di] = __builtin_amdgcn_mfma_f32_16x16x32_bf16(af, bfv, acc[di], 0, 0, 0);
        }
    }
    // per-row sum: lanes {l15, l15+16, l15+32, l15+48} hold partials
    ls += __shfl_xor(ls, 16);
    ls += __shfl_xor(ls, 32);
    if (quad == 0) atomicAdd(&lsum[(size_t)bh * 64 + cb + l15], ls);

    const int c = cb + quad * 4;
#pragma unroll
    for (int di = 0; di < 4; ++di) {
        int d = di * 16 + l15;
#pragma unroll
        for (int r = 0; r < 4; ++r)
            atomicAdd(&ctxT[((size_t)bh * 64 + d) * 64 + c + r], acc[di][r]);
    }
}

// W_eff[b][o][h*64+c] = (1/l_c) * sum_d wout[o][h*64+d]*ctxT[b][h][d][c]
// wout read is wave-uniform (scalar); ctxT read coalesces on c (lane index).
__global__ __launch_bounds__(256) void k_weff(const float* __restrict__ wout,
                                              const float* __restrict__ ctxT,
                                              const float* __restrict__ lsum,
                                              u16* __restrict__ weff) {
    int idx = blockIdx.x * 256 + threadIdx.x;   // 16*512*512
    int b = idx >> 18;
    int o = (idx >> 9) & 511;
    int hc = idx & 511;
    int h = hc >> 6, c = hc & 63;
    const float* wr = wout + o * 512 + h * 64;          // uniform across wave
    const float* cr = ctxT + ((size_t)b * 8 + h) * 4096 + c;  // lane-coalesced
    float s = 0.f;
#pragma unroll
    for (int d = 0; d < 64; ++d) s += wr[d] * cr[d * 64];
    s *= 1.0f / lsum[((size_t)b * 8 + h) * 64 + c];
    weff[idx] = f2bf(s);
}

// ---------------- GEMM2: Y_b = W_eff_b(512x512) @ Q_b + b_out -----------------
__global__ __launch_bounds__(256, 2) void k_gemm2(
        const u16* __restrict__ weff, const u16* __restrict__ qt,
        const float* __restrict__ bout, float* __restrict__ y) {
    __shared__ __align__(16) u16 As[128 * 64];
    __shared__ __align__(16) u16 Bs[128 * 64];
    const int t = threadIdx.x;
    const int gid = blockIdx.x;
    const int xcd = gid & 7;
    const int j = gid >> 3;
    const int ot = j & 3;
    const int bn = (j >> 2) * 8 + xcd;   // 0..511
    const int b = bn >> 5;
    const int nt = bn & 31;

    const int lane = t & 63, w = t >> 6;
    const int l15 = lane & 15, quad = lane >> 4;
    const int wm = (w >> 1) * 64, wn = (w & 1) * 64;
    const int srow = t >> 3;
    const int kc = (t & 7) * 8;

    const u16* Ab = weff + (size_t)b * 512 * 512 + (size_t)(ot * 128) * CD;
    const u16* Bb = qt + (size_t)b * NN * CD + (size_t)(nt * 128) * CD;

    f32x4 acc[4][4] = {};

    for (int k0 = 0; k0 < CD; k0 += 64) {
        __syncthreads();
        gl2lds16(Ab + (size_t)(srow     ) * CD + k0 + kc, &As[t * 8]);
        gl2lds16(Ab + (size_t)(srow + 32) * CD + k0 + kc, &As[2048 + t * 8]);
        gl2lds16(Ab + (size_t)(srow + 64) * CD + k0 + kc, &As[4096 + t * 8]);
        gl2lds16(Ab + (size_t)(srow + 96) * CD + k0 + kc, &As[6144 + t * 8]);
        gl2lds16(Bb + (size_t)(srow     ) * CD + k0 + kc, &Bs[t * 8]);
        gl2lds16(Bb + (size_t)(srow + 32) * CD + k0 + kc, &Bs[2048 + t * 8]);
        gl2lds16(Bb + (size_t)(srow + 64) * CD + k0 + kc, &Bs[4096 + t * 8]);
        gl2lds16(Bb + (size_t)(srow + 96) * CD + k0 + kc, &Bs[6144 + t * 8]);
        __syncthreads();
#pragma unroll
        for (int h = 0; h < 2; ++h) {
            bf16x8 af[4], bfr[4];
#pragma unroll
            for (int mi = 0; mi < 4; ++mi)
                af[mi] = *(const bf16x8*)&As[(wm + mi * 16 + l15) * 64 + h * 32 + quad * 8];
#pragma unroll
            for (int ni = 0; ni < 4; ++ni)
                bfr[ni] = *(const bf16x8*)&Bs[(wn + ni * 16 + l15) * 64 + h * 32 + quad * 8];
#pragma unroll
            for (int mi = 0; mi < 4; ++mi)
#pragma unroll
                for (int ni = 0; ni < 4; ++ni)
                    acc[mi][ni] = __builtin_amdgcn_mfma_f32_16x16x32_bf16(
                        af[mi], bfr[ni], acc[mi][ni], 0, 0, 0);
        }
    }

#pragma unroll
    for (int mi = 0; mi < 4; ++mi) {
        int o = ot * 128 + wm + mi * 16 + quad * 4;
#pragma unroll
        for (int ni = 0; ni < 4; ++ni) {
            int nc = nt * 128 + wn + ni * 16 + l15;
#pragma unroll
            for (int r = 0; r < 4; ++r)
                y[((size_t)(b * 512 + o + r)) * NN + nc] = acc[mi][ni][r] + bout[o + r];
        }
    }
}

extern "C" void kernel_launch(void* const* d_in, const int* in_sizes, int n_in,
                              void* d_out, int out_size, void* d_ws, size_t ws_size,
                              hipStream_t stream) {
    const float* x    = (const float*)d_in[0];
    const float* wqkv = (const float*)d_in[1];
    const float* wout = (const float*)d_in[2];
    const float* bout = (const float*)d_in[3];
    float* y = (float*)d_out;

    char* ws = (char*)d_ws;
    u16*   xt   = (u16*)(ws);                       //  67,108,864  xt[b][n][c] bf16
    u16*   wqb  = (u16*)(ws + 67108864);            //   1,572,864  wqkv bf16
    u16*   qt   = (u16*)(ws + 68681728);            //  67,108,864  Qt[b][n][c] bf16
    u16*   kbuf = (u16*)(ws + 135790592);           //  67,108,864  K raw [b*512][n]
    u16*   vbuf = (u16*)(ws + 202899456);           //  67,108,864  V [b*512][n]
    float* ctxT = (float*)(ws + 270008320);         //   2,097,152  contextT fp32 (unnorm)
    float* lsum = (float*)(ws + 272105472);         //      32,768  row sums
    u16*   weff = (u16*)(ws + 272138240);           //   8,388,608  W_eff bf16

    hipMemsetAsync(ctxT, 0, 2097152 + 32768, stream);  // ctxT + lsum contiguous

    k_convert<<<(O3 * CD + 255) / 256, 256, 0, stream>>>(wqkv, wqb, O3 * CD);
    k_transpose_x<<<dim3(64 * 8, NB), 256, 0, stream>>>(x, xt);
    k_gemm1<<<12 * 32 * NB, 256, 0, stream>>>(wqb, xt, qt, kbuf, vbuf);
    k_ctx<<<dim3(4, NB * 8), 256, 0, stream>>>(kbuf, vbuf, ctxT, lsum);
    k_weff<<<(NB * 512 * 512) / 256, 256, 0, stream>>>(wout, ctxT, lsum, weff);
    k_gemm2<<<4 * 32 * NB, 256, 0, stream>>>(weff, qt, bout, y);
}